// Round 8
// baseline (279.067 us; speedup 1.0000x reference)
//
#include <hip/hip_runtime.h>
#include <hip/hip_bf16.h>

typedef __hip_bfloat16 bf16;
typedef __attribute__((ext_vector_type(8))) short bf16x8;   // 8 bf16 = 4 VGPRs (MFMA A/B frag)
typedef __attribute__((ext_vector_type(4))) float f32x4;    // MFMA C/D frag
typedef unsigned int u32;
typedef unsigned short u16;

#define MFMA(a,b,c) __builtin_amdgcn_mfma_f32_16x16x32_bf16((a),(b),(c),0,0,0)

__device__ __forceinline__ u16 f32_to_bf16_rtne(float f) {
  u32 b = __builtin_bit_cast(u32, f);
  b += 0x7FFFu + ((b >> 16) & 1u);
  return (u16)(b >> 16);
}
__device__ __forceinline__ u32 pk2bf(float a, float b) {
  u32 ua = __builtin_bit_cast(u32, a); ua += 0x7FFFu + ((ua >> 16) & 1u);
  u32 ub = __builtin_bit_cast(u32, b); ub += 0x7FFFu + ((ub >> 16) & 1u);
  return __builtin_amdgcn_perm(ub, ua, 0x07060302u);
}
__device__ __forceinline__ u32 pk2bf_rtz(float a, float b) {
  return __builtin_amdgcn_perm(__builtin_bit_cast(u32, b),
                               __builtin_bit_cast(u32, a), 0x07060302u);
}
__device__ __forceinline__ uint4 cvt8(uint4 lo, uint4 hi) {
  const float4 fl = __builtin_bit_cast(float4, lo);
  const float4 fh = __builtin_bit_cast(float4, hi);
  uint4 r;
  r.x = pk2bf(fl.x, fl.y); r.y = pk2bf(fl.z, fl.w);
  r.z = pk2bf(fh.x, fh.y); r.w = pk2bf(fh.z, fh.w);
  return r;
}

// barriers
__device__ __forceinline__ void barrier_lgkm() {   // LDS drained; vmem stays in flight
  asm volatile("s_waitcnt lgkmcnt(0)\n\ts_barrier" ::: "memory");
}

// async global->LDS DMA, 16B/lane; LDS dest = wave-uniform base + lane*16B
typedef const __attribute__((address_space(1))) void* gas_ptr;
typedef __attribute__((address_space(3))) void* las_ptr;
__device__ __forceinline__ void gload_lds16(const void* g, void* l) {
  __builtin_amdgcn_global_load_lds((gas_ptr)g, (las_ptr)l, 16, 0, 0);
}

static constexpr float SL2E = 0.125f * 1.44269504f;  // 1/sqrt(dh) * log2(e)

// ---------------------------------------------------------------------------
// f32 -> bf16 cast, WEIGHTS ONLY (x is cast in-flight inside gemm_qkv).
// grid 2048: blocks [512m, 512m+512) handle Wq/Wk/Wv -> wqkv, Wo -> wob.
// ---------------------------------------------------------------------------
__global__ __launch_bounds__(256)
void cast_w(const float* __restrict__ wq, const float* __restrict__ wk,
            const float* __restrict__ wv, const float* __restrict__ wo,
            u16* __restrict__ wqkv, u16* __restrict__ wob) {
  const size_t DD8 = (size_t)1024 * 1024 / 8;
  const int m = blockIdx.x >> 9;
  const size_t i = ((size_t)(blockIdx.x & 511)) * 256 + threadIdx.x;
  const float* src = (m == 0) ? wq : (m == 1) ? wk : (m == 2) ? wv : wo;
  u16* dst = (m < 3) ? (wqkv + (size_t)m * DD8 * 8) : wob;
  const float4* s = (const float4*)src + i * 2;
  ((uint4*)dst)[i] = cvt8(__builtin_bit_cast(uint4, s[0]),
                          __builtin_bit_cast(uint4, s[1]));
}

// ---------------------------------------------------------------------------
// QKV GEMM with FUSED A-cast: 2-phase (R4 structure), BM=128 x BN=256,
// BK=64, 512 thr = 8 waves (2M x 4N), per-wave 64x64, acc[4][4].
// A = x (f32), cast to bf16 in-register during staging (reg->cvt8->ds_write,
// XOR-swizzled granules, bank-balanced).  B = W (bf16) via gload_lds with
// counted vmcnt.  Removes the xb HBM round-trip (33.6 MB) + x-cast kernel.
// Per tile t:  ph1: issue A(t+1) f32 loads; ds_read all-B + A-lo; barrier;
//   16 MFMA; lgkm-barrier.  ph2: ds_read A-hi; cvt8+ds_write A(t+1)
//   (implicit vmcnt(0) here also retires B(t+1), which has ~1 tile flight);
//   stage B(t+2) via gload_lds (stays in flight across boundary);
//   barrier; 16 MFMA; boundary vmcnt(4) lgkm(0) barrier.
// ---------------------------------------------------------------------------
__global__ __launch_bounds__(512, 2)
void gemm_qkv(const float* __restrict__ A, const bf16* __restrict__ W,
              const float* __restrict__ b0, const float* __restrict__ b1,
              const float* __restrict__ b2, u16* __restrict__ o0,
              u16* __restrict__ o1, u16* __restrict__ o2,
              int M, int N, int K)
{
  __shared__ __align__(16) bf16 AsB[2][128 * 64];
  __shared__ __align__(16) bf16 BsB[2][256 * 64];

  const int nwg = gridDim.x * gridDim.y;   // 768 (%8 == 0)
  const int raw = blockIdx.y * gridDim.x + blockIdx.x;
  const int vwg = (raw & 7) * (nwg >> 3) + (raw >> 3);
  const int NT  = gridDim.y;               // 12
  const int bx  = vwg / NT, by = vwg - bx * NT;
  const int m0  = bx * 128, n0 = by * 256;

  const int tid  = threadIdx.x;
  const int wv   = tid >> 6, lane = tid & 63;
  const int quad = lane >> 4, l16 = lane & 15;
  const int wm   = wv >> 2, wn = wv & 3;   // wave grid 2M x 4N
  const int r7   = l16 & 7;

  // ---- B staging (gload_lds, pre-swizzled source granule) ----
  const int rr8 = tid >> 3, g = tid & 7;
  const int sg8 = (g ^ (rr8 & 7)) * 8;
  const bf16* wS = W + (size_t)(n0 + rr8) * K + sg8;
  const int ldstW = wv * 512;              // wave-uniform LDS offset in chunk

#define STB8(buf, kt) do { \
    gload_lds16(wS + (size_t)(kt) * 64,                      &BsB[buf][ldstW]); \
    gload_lds16(wS + (size_t)64 * K + (size_t)(kt) * 64,     &BsB[buf][4096 + ldstW]); \
    gload_lds16(wS + (size_t)128 * K + (size_t)(kt) * 64,    &BsB[buf][8192 + ldstW]); \
    gload_lds16(wS + (size_t)192 * K + (size_t)(kt) * 64,    &BsB[buf][12288 + ldstW]); \
  } while (0)

  // ---- A staging (f32 load -> cvt8 -> swizzled ds_write) ----
  const int arw = tid >> 2, aj = tid & 3, ae = arw & 7;
  const float* aF = A + (size_t)(m0 + arw) * K + aj * 16;
  const int aw0 = arw * 64 + (((2 * aj) ^ ae) * 8);
  const int aw1 = arw * 64 + ((((2 * aj) + 1) ^ ae) * 8);

  int aoff[4], boff[4];
#pragma unroll
  for (int mt = 0; mt < 4; ++mt) aoff[mt] = (wm * 64 + mt * 16 + l16) * 64;
#pragma unroll
  for (int nt = 0; nt < 4; ++nt) boff[nt] = (wn * 64 + nt * 16 + l16) * 64;
  const int k0o = (quad ^ r7) * 8;
  const int k1o = ((4 + quad) ^ r7) * 8;

  f32x4 acc[4][4] = {};
  bf16x8 bfr[4][2], afr[2][2];
  uint4 pa0, pa1, pa2, pa3;                // named A-prefetch regs (no scratch)

  const int nk = K >> 6;   // 16

  // ---- prologue: A(0) cast+write; B(0) landed; B(1) in flight ----
  pa0 = *(const uint4*)(aF);      pa1 = *(const uint4*)(aF + 4);
  pa2 = *(const uint4*)(aF + 8);  pa3 = *(const uint4*)(aF + 12);
  *(uint4*)(AsB[0] + aw0) = cvt8(pa0, pa1);
  *(uint4*)(AsB[0] + aw1) = cvt8(pa2, pa3);
  STB8(0, 0);
  STB8(1, 1);
  asm volatile("s_waitcnt vmcnt(4) lgkmcnt(0)\n\ts_barrier" ::: "memory");

  for (int t = 0; t < nk; ++t) {
    const int c = t & 1;
    const bf16* Ac = AsB[c];
    const bf16* Bc = BsB[c];

    // phase 1: issue A(t+1) f32 loads; ds_read all-B + A-lo; MFMA mt0-1
    if (t + 1 < nk) {
      const float* ap = aF + (t + 1) * 64;
      pa0 = *(const uint4*)(ap);      pa1 = *(const uint4*)(ap + 4);
      pa2 = *(const uint4*)(ap + 8);  pa3 = *(const uint4*)(ap + 12);
    }
#pragma unroll
    for (int nt = 0; nt < 4; ++nt) {
      bfr[nt][0] = *(const bf16x8*)(Bc + boff[nt] + k0o);
      bfr[nt][1] = *(const bf16x8*)(Bc + boff[nt] + k1o);
    }
#pragma unroll
    for (int mt = 0; mt < 2; ++mt) {
      afr[mt][0] = *(const bf16x8*)(Ac + aoff[mt] + k0o);
      afr[mt][1] = *(const bf16x8*)(Ac + aoff[mt] + k1o);
    }
    asm volatile("s_barrier" ::: "memory");
    __builtin_amdgcn_s_setprio(1);
#pragma unroll
    for (int mt = 0; mt < 2; ++mt)
#pragma unroll
      for (int nt = 0; nt < 4; ++nt) {
        acc[mt][nt] = MFMA(afr[mt][0], bfr[nt][0], acc[mt][nt]);
        acc[mt][nt] = MFMA(afr[mt][1], bfr[nt][1], acc[mt][nt]);
      }
    __builtin_amdgcn_s_setprio(0);
    asm volatile("s_waitcnt lgkmcnt(0)\n\ts_barrier" ::: "memory");

    // phase 2: ds_read A-hi; cast+write A(t+1); stage B(t+2); MFMA mt2-3
#pragma unroll
    for (int mt = 0; mt < 2; ++mt) {
      afr[mt][0] = *(const bf16x8*)(Ac + aoff[mt + 2] + k0o);
      afr[mt][1] = *(const bf16x8*)(Ac + aoff[mt + 2] + k1o);
    }
    if (t + 1 < nk) {
      bf16* Ad = AsB[(t + 1) & 1];
      *(uint4*)(Ad + aw0) = cvt8(pa0, pa1);   // implicit vmcnt wait on pa*
      *(uint4*)(Ad + aw1) = cvt8(pa2, pa3);
    }
    if (t + 2 < nk) STB8(c, t + 2);
    asm volatile("s_barrier" ::: "memory");
    __builtin_amdgcn_s_setprio(1);
#pragma unroll
    for (int mt = 0; mt < 2; ++mt)
#pragma unroll
      for (int nt = 0; nt < 4; ++nt) {
        acc[mt + 2][nt] = MFMA(afr[mt][0], bfr[nt][0], acc[mt + 2][nt]);
        acc[mt + 2][nt] = MFMA(afr[mt][1], bfr[nt][1], acc[mt + 2][nt]);
      }
    __builtin_amdgcn_s_setprio(0);
    if (t + 1 < nk) {
      if (t + 2 < nk)
        asm volatile("s_waitcnt vmcnt(4) lgkmcnt(0)\n\ts_barrier" ::: "memory");
      else
        asm volatile("s_waitcnt vmcnt(0) lgkmcnt(0)\n\ts_barrier" ::: "memory");
    }
  }
#undef STB8

  // epilogue: C/D layout col = lane&15, row = quad*4 + reg
  const int band = n0 >> 10;
  const float* bias = (band == 0) ? b0 : (band == 1) ? b1 : b2;
#pragma unroll
  for (int nt = 0; nt < 4; ++nt) {
    const int col = n0 + wn * 64 + nt * 16 + l16;
    const int cl  = col & 1023;
    const float bv = bias[cl];
#pragma unroll
    for (int mt = 0; mt < 4; ++mt) {
      const int rbase = m0 + wm * 64 + mt * 16 + quad * 4;
      if (band == 2) {
        const int hh = cl >> 6, dd = cl & 63;
        const int bb = rbase >> 12, tl = rbase & 4095;
        u16* dst = o2 + ((size_t)((bb * 16 + hh) * 64 + dd)) * 4096 + tl;
        uint2 pk;
        pk.x = pk2bf(acc[mt][nt][0] + bv, acc[mt][nt][1] + bv);
        pk.y = pk2bf(acc[mt][nt][2] + bv, acc[mt][nt][3] + bv);
        *(uint2*)dst = pk;
      } else {
        u16* dst = (band == 0) ? o0 : o1;
        const float sc = (band == 0) ? SL2E : 1.0f;
#pragma unroll
        for (int r = 0; r < 4; ++r)
          dst[(size_t)(rbase + r) * 1024 + cl] =
              f32_to_bf16_rtne((acc[mt][nt][r] + bv) * sc);
      }
    }
  }
}

// ---------------------------------------------------------------------------
// Out-projection: 128x128 GEMM, m97 structure (gload_lds + __syncthreads),
// 512 blocks, 32 KiB LDS -> multiple blocks/CU.
// ---------------------------------------------------------------------------
__global__ __launch_bounds__(256)
void gemm_out(const bf16* __restrict__ A, const bf16* __restrict__ W,
              const float* __restrict__ bias, float* __restrict__ out,
              int M, int N, int K)
{
  __shared__ bf16 As[128 * 64];
  __shared__ bf16 Bs[128 * 64];

  const int tid  = threadIdx.x;
  const int wave = tid >> 6, lane = tid & 63;
  const int quad = lane >> 4, l16 = lane & 15;
  const int wm   = wave >> 1, wn  = wave & 1;
  const int m0   = blockIdx.x * 128, n0 = blockIdx.y * 128;

  const int srow = lane >> 3;
  const int sg   = lane & 7;
  const size_t rgs = (size_t)8 * K;
  const bf16* aSrc = A + (size_t)(m0 + wave * 32 + srow) * K + ((sg ^ srow) * 8);
  const bf16* wSrc = W + (size_t)(n0 + wave * 32 + srow) * K + ((sg ^ srow) * 8);
  bf16* aB = As + wave * 32 * 64;
  bf16* wB = Bs + wave * 32 * 64;

  const int niter = K >> 6;

  f32x4 acc[4][4] = {};

  const int arow[4] = { (wm * 64 + 0 * 16 + l16) * 64, (wm * 64 + 1 * 16 + l16) * 64,
                        (wm * 64 + 2 * 16 + l16) * 64, (wm * 64 + 3 * 16 + l16) * 64 };
  const int brow[4] = { (wn * 64 + 0 * 16 + l16) * 64, (wn * 64 + 1 * 16 + l16) * 64,
                        (wn * 64 + 2 * 16 + l16) * 64, (wn * 64 + 3 * 16 + l16) * 64 };
  const int r7 = l16 & 7;

  for (int t = 0; t < niter; ++t) {
    gload_lds16(aSrc,            aB);
    gload_lds16(aSrc + rgs,      aB + 512);
    gload_lds16(aSrc + 2 * rgs,  aB + 1024);
    gload_lds16(aSrc + 3 * rgs,  aB + 1536);
    gload_lds16(wSrc,            wB);
    gload_lds16(wSrc + rgs,      wB + 512);
    gload_lds16(wSrc + 2 * rgs,  wB + 1024);
    gload_lds16(wSrc + 3 * rgs,  wB + 1536);
    aSrc += 64; wSrc += 64;
    __syncthreads();

#pragma unroll
    for (int kk = 0; kk < 2; ++kk) {
      bf16x8 af[4], bw[4];
#pragma unroll
      for (int mt = 0; mt < 4; ++mt)
        af[mt] = *(const bf16x8*)(As + arow[mt] + (((kk * 4 + quad) ^ r7) * 8));
#pragma unroll
      for (int nt = 0; nt < 4; ++nt)
        bw[nt] = *(const bf16x8*)(Bs + brow[nt] + (((kk * 4 + quad) ^ r7) * 8));
#pragma unroll
      for (int mt = 0; mt < 4; ++mt)
#pragma unroll
        for (int nt = 0; nt < 4; ++nt)
          acc[mt][nt] = MFMA(af[mt], bw[nt], acc[mt][nt]);
    }
    if (t + 1 < niter) __syncthreads();
  }

#pragma unroll
  for (int nt = 0; nt < 4; ++nt) {
    const int col = n0 + wn * 64 + nt * 16 + l16;
    const float bv = bias[col & 1023];
#pragma unroll
    for (int mt = 0; mt < 4; ++mt) {
      const int rbase = m0 + wm * 64 + mt * 16 + quad * 4;
#pragma unroll
      for (int r = 0; r < 4; ++r)
        out[(size_t)(rbase + r) * N + col] = acc[mt][nt][r] + bv;
    }
  }
}

// ---------------------------------------------------------------------------
// Sliding-window attention, S^T formulation, fixed-max softmax,
// double-buffered K/V LDS, one lgkm barrier per tile (original, proven).
// ---------------------------------------------------------------------------
__global__ __launch_bounds__(256)
void attn_swin(const bf16* __restrict__ qb, const bf16* __restrict__ kb,
               const bf16* __restrict__ vtb, u16* __restrict__ ctx)
{
  __shared__ __align__(16) bf16 Ks[2][64 * 72];
  __shared__ __align__(16) bf16 Vts[2][64 * 72];

  int bid = blockIdx.x;
  const int g  = bid & 255, qt = bid >> 8;
  const int h  = g & 15, c = (g >> 4) & 7, b = g >> 7;

  const int tid  = threadIdx.x;
  const int w    = tid >> 6, lane = tid & 63;
  const int quad = lane >> 4, l16 = lane & 15;

  const int tq0  = c * 512 + qt * 128;
  const int hoff = h * 64;
  const int kstart = (c == 0) ? 0 : (c - 1) * 512;
  const int nkt    = (c == 0) ? 8 : 16;

  bf16x8 qf[2][2];
#pragma unroll
  for (int u = 0; u < 2; ++u) {
    const bf16* qr = qb + ((size_t)(b * 4096 + tq0 + w * 32 + u * 16 + l16)) * 1024 + hoff;
    qf[u][0] = *(const bf16x8*)(qr + quad * 8);
    qf[u][1] = *(const bf16x8*)(qr + 32 + quad * 8);
  }

  const int m    = tid >> 2;
  const int cseg = (tid & 3) * 16;
  const int sig  = (((m >> 4) & 1) << 5) | (((m >> 2) & 3) << 3)
                 | (((m >> 5) & 1) << 2) | (m & 3);
  const bf16* kgp = kb + ((size_t)(b * 4096 + kstart + sig)) * 1024 + hoff + cseg;
  const bf16* vgp = vtb + ((size_t)((b * 16 + h) * 64 + m)) * 4096 + kstart + cseg;
  const int soff = m * 72 + cseg;

  float l_i[2] = {0.f, 0.f};
  f32x4 o[2][4] = {};

  uint4 ka0 = *(const uint4*)(kgp), ka1 = *(const uint4*)(kgp + 8);
  uint4 va0 = *(const uint4*)(vgp), va1 = *(const uint4*)(vgp + 8);
  kgp += (size_t)64 * 1024; vgp += 64;
  *(uint4*)(Ks[0] + soff) = ka0; *(uint4*)(Ks[0] + soff + 8) = ka1;
  *(uint4*)(Vts[0] + soff) = va0; *(uint4*)(Vts[0] + soff + 8) = va1;
  ka0 = *(const uint4*)(kgp); ka1 = *(const uint4*)(kgp + 8);
  va0 = *(const uint4*)(vgp); va1 = *(const uint4*)(vgp + 8);
  kgp += (size_t)64 * 1024; vgp += 64;
  barrier_lgkm();

  typedef union { u32 d[4]; bf16x8 v; } fragu;

  auto compute = [&](const bf16* ksb, const bf16* vtsb) {
    f32x4 s[2][4] = {};
#pragma unroll
    for (int kt = 0; kt < 4; ++kt) {
      const bf16* kr = ksb + (kt * 16 + l16) * 72;
      bf16x8 kf0 = *(const bf16x8*)(kr + quad * 8);
      bf16x8 kf1 = *(const bf16x8*)(kr + 32 + quad * 8);
      s[0][kt] = MFMA(kf0, qf[0][0], s[0][kt]);
      s[0][kt] = MFMA(kf1, qf[0][1], s[0][kt]);
      s[1][kt] = MFMA(kf0, qf[1][0], s[1][kt]);
      s[1][kt] = MFMA(kf1, qf[1][1], s[1][kt]);
    }
    fragu pf[2][2];
#pragma unroll
    for (int u = 0; u < 2; ++u) {
      float rs = 0.f;
#pragma unroll
      for (int kt = 0; kt < 4; ++kt)
#pragma unroll
        for (int r = 0; r < 4; ++r) {
          const float p = __builtin_amdgcn_exp2f(s[u][kt][r]);
          s[u][kt][r] = p;
          rs += p;
        }
      rs += __shfl_xor(rs, 16);
      rs += __shfl_xor(rs, 32);
      l_i[u] += rs;
#pragma unroll
      for (int hh = 0; hh < 2; ++hh)
#pragma unroll
        for (int dw = 0; dw < 4; ++dw) {
          const int kt = 2 * (dw >> 1) + hh, r0 = 2 * (dw & 1);
          pf[u][hh].d[dw] = pk2bf_rtz(s[u][kt][r0], s[u][kt][r0 + 1]);
        }
    }
#pragma unroll
    for (int dt = 0; dt < 4; ++dt) {
      const bf16* vr = vtsb + (dt * 16 + l16) * 72;
      bf16x8 vf0 = *(const bf16x8*)(vr + quad * 8);
      bf16x8 vf1 = *(const bf16x8*)(vr + 32 + quad * 8);
      o[0][dt] = MFMA(vf0, pf[0][0].v, o[0][dt]);
      o[0][dt] = MFMA(vf1, pf[0][1].v, o[0][dt]);
      o[1][dt] = MFMA(vf0, pf[1][0].v, o[1][dt]);
      o[1][dt] = MFMA(vf1, pf[1][1].v, o[1][dt]);
    }
  };

  for (int t = 0; t < nkt; t += 2) {
    *(uint4*)(Ks[1] + soff) = ka0; *(uint4*)(Ks[1] + soff + 8) = ka1;
    *(uint4*)(Vts[1] + soff) = va0; *(uint4*)(Vts[1] + soff + 8) = va1;
    if (t + 2 < nkt) {
      ka0 = *(const uint4*)(kgp); ka1 = *(const uint4*)(kgp + 8);
      va0 = *(const uint4*)(vgp); va1 = *(const uint4*)(vgp + 8);
      kgp += (size_t)64 * 1024; vgp += 64;
    }
    compute(Ks[0], Vts[0]);
    barrier_lgkm();

    if (t + 2 < nkt) {
      *(uint4*)(Ks[0] + soff) = ka0; *(uint4*)(Ks[0] + soff + 8) = ka1;
      *(uint4*)(Vts[0] + soff) = va0; *(uint4*)(Vts[0] + soff + 8) = va1;
      if (t + 3 < nkt) {
        ka0 = *(const uint4*)(kgp); ka1 = *(const uint4*)(kgp + 8);
        va0 = *(const uint4*)(vgp); va1 = *(const uint4*)(vgp + 8);
        kgp += (size_t)64 * 1024; vgp += 64;
      }
    }
    compute(Ks[1], Vts[1]);
    barrier_lgkm();
  }

#pragma unroll
  for (int u = 0; u < 2; ++u) {
    const float inv = 1.0f / l_i[u];
    const int qrow = tq0 + w * 32 + u * 16 + l16;
    u16* crow = ctx + ((size_t)(b * 4096 + qrow)) * 1024 + hoff;
#pragma unroll
    for (int dt = 0; dt < 4; ++dt) {
      uint2 pk;
      pk.x = pk2bf(o[u][dt][0] * inv, o[u][dt][1] * inv);
      pk.y = pk2bf(o[u][dt][2] * inv, o[u][dt][3] * inv);
      *(uint2*)(crow + dt * 16 + quad * 4) = pk;
    }
  }
}

// ---------------------------------------------------------------------------
extern "C" void kernel_launch(void* const* d_in, const int* in_sizes, int n_in,
                              void* d_out, int out_size, void* d_ws, size_t ws_size,
                              hipStream_t stream) {
  const float* x  = (const float*)d_in[0];
  const float* Wq = (const float*)d_in[1];
  const float* bq = (const float*)d_in[2];
  const float* Wk = (const float*)d_in[3];
  const float* bk = (const float*)d_in[4];
  const float* Wv = (const float*)d_in[5];
  const float* bv = (const float*)d_in[6];
  const float* Wo = (const float*)d_in[7];
  const float* bo = (const float*)d_in[8];

  const size_t MD = (size_t)8192 * 1024;   // [B*L, D] elements
  const size_t DD = (size_t)1024 * 1024;   // [D, D] elements

  char* ws = (char*)d_ws;
  u16*  Wqkvb = (u16*)ws;                     ws += 3 * DD * 2;
  u16*  Wob   = (u16*)ws;                     ws += DD * 2;
  u16*  qbuf  = (u16*)ws;                     ws += MD * 2;
  u16*  kbuf  = (u16*)ws;                     ws += MD * 2;
  u16*  vtb   = (u16*)ws;                     ws += MD * 2;
  u16*  ctx   = (u16*)ws;                     // + MD*2  (~72 MB total)

  cast_w<<<dim3(2048), dim3(256), 0, stream>>>(Wq, Wk, Wv, Wo, Wqkvb, Wob);

  // fused QKV projection; A = x (f32) cast in-flight during staging
  gemm_qkv<<<dim3(64, 12), dim3(512), 0, stream>>>(
      x, (const bf16*)Wqkvb, bq, bk, bv,
      qbuf, kbuf, vtb, 8192, 3072, 1024);

  attn_swin<<<dim3(1024), dim3(256), 0, stream>>>(
      (const bf16*)qbuf, (const bf16*)kbuf, (const bf16*)vtb, ctx);

  gemm_out<<<dim3(64, 8), dim3(256), 0, stream>>>(
      (const bf16*)ctx, (const bf16*)Wob, bo, (float*)d_out, 8192, 1024, 1024);
}

// Round 9
// 243.138 us; speedup vs baseline: 1.1478x; 1.1478x over previous
//
#include <hip/hip_runtime.h>
#include <hip/hip_bf16.h>

typedef __hip_bfloat16 bf16;
typedef __attribute__((ext_vector_type(8))) short bf16x8;   // 8 bf16 = 4 VGPRs (MFMA A/B frag)
typedef __attribute__((ext_vector_type(4))) float f32x4;    // MFMA C/D frag
typedef unsigned int u32;
typedef unsigned short u16;

#define MFMA(a,b,c) __builtin_amdgcn_mfma_f32_16x16x32_bf16((a),(b),(c),0,0,0)

__device__ __forceinline__ u16 f32_to_bf16_rtne(float f) {
  u32 b = __builtin_bit_cast(u32, f);
  b += 0x7FFFu + ((b >> 16) & 1u);
  return (u16)(b >> 16);
}
// pack two f32 -> bf16 pair, RTNE
__device__ __forceinline__ u32 pk2bf(float a, float b) {
  u32 ua = __builtin_bit_cast(u32, a); ua += 0x7FFFu + ((ua >> 16) & 1u);
  u32 ub = __builtin_bit_cast(u32, b); ub += 0x7FFFu + ((ub >> 16) & 1u);
  return __builtin_amdgcn_perm(ub, ua, 0x07060302u);
}
// pack two f32 -> bf16 pair, RTZ (P-matrix hot path: 1 v_perm)
__device__ __forceinline__ u32 pk2bf_rtz(float a, float b) {
  return __builtin_amdgcn_perm(__builtin_bit_cast(u32, b),
                               __builtin_bit_cast(u32, a), 0x07060302u);
}
// 8 f32 (two uint4) -> 8 bf16 (one uint4), RTNE
__device__ __forceinline__ uint4 cvt8(uint4 lo, uint4 hi) {
  const float4 fl = __builtin_bit_cast(float4, lo);
  const float4 fh = __builtin_bit_cast(float4, hi);
  uint4 r;
  r.x = pk2bf(fl.x, fl.y); r.y = pk2bf(fl.z, fl.w);
  r.z = pk2bf(fh.x, fh.y); r.w = pk2bf(fh.z, fh.w);
  return r;
}

// lgkm-only barrier: LDS ops drained, but outstanding global->reg prefetch
// loads stay IN FLIGHT across the barrier (no vmcnt(0) drain).
__device__ __forceinline__ void barrier_lgkm() {
  asm volatile("s_waitcnt lgkmcnt(0)\n\ts_barrier" ::: "memory");
}

// async global->LDS DMA, 16B/lane; LDS dest = wave-uniform base + lane*16B
typedef const __attribute__((address_space(1))) void* gas_ptr;
typedef __attribute__((address_space(3))) void* las_ptr;
__device__ __forceinline__ void gload_lds16(const void* g, void* l) {
  __builtin_amdgcn_global_load_lds((gas_ptr)g, (las_ptr)l, 16, 0, 0);
}

static constexpr float SL2E = 0.125f * 1.44269504f;  // 1/sqrt(dh) * log2(e)

// ---------------------------------------------------------------------------
// Weight cast f32 -> bf16 (x is cast inside the QKV GEMM's staging path).
// grid 2048: blocks [512m, 512m+512) handle Wq/Wk/Wv -> wqkv, Wo -> wob.
// ---------------------------------------------------------------------------
__global__ __launch_bounds__(256)
void cast_w(const float* __restrict__ wq, const float* __restrict__ wk,
            const float* __restrict__ wv, const float* __restrict__ wo,
            u16* __restrict__ wqkv, u16* __restrict__ wob) {
  const size_t DD8 = (size_t)1024 * 1024 / 8;
  const int m = blockIdx.x >> 9;
  const size_t i = ((size_t)(blockIdx.x & 511)) * 256 + threadIdx.x;
  const float* src = (m == 0) ? wq : (m == 1) ? wk : (m == 2) ? wv : wo;
  u16* dst = (m < 3) ? (wqkv + (size_t)m * DD8 * 8) : wob;
  const float4* s = (const float4*)src + i * 2;
  uint4 v = cvt8(__builtin_bit_cast(uint4, s[0]), __builtin_bit_cast(uint4, s[1]));
  ((uint4*)dst)[i] = v;
}

// ---------------------------------------------------------------------------
// QKV GEMM (R0 structure, best measured QKV+cast unit: 82.4 + 4 us).
// C = A @ W^T + bias.  BM=BN=128, BK=64, 256 thr (2x2 waves).
// Named prefetch regs (no scratch), lgkm-only barriers, XOR-swizzled LDS
// (conflicts = 0).  A is f32 (x), converted to bf16 in-register during
// staging.  Band 0 -> o0 = qb (pre-scaled SL2E); band 1 -> o1 = kb;
// band 2 -> o2 = vtb[(b*16+h)*64+d][4096] (transposed V).
// ---------------------------------------------------------------------------
__global__ __launch_bounds__(256)
void gemm_bt(const float* __restrict__ Asrc, const bf16* __restrict__ W,
             const float* __restrict__ b0, const float* __restrict__ b1,
             const float* __restrict__ b2, u16* __restrict__ o0,
             u16* __restrict__ o1, u16* __restrict__ o2,
             int M, int N, int K)
{
  __shared__ bf16 As[128 * 64];
  __shared__ bf16 Bs[128 * 64];

  const int tid  = threadIdx.x;
  const int wave = tid >> 6, lane = tid & 63;
  const int quad = lane >> 4, l16 = lane & 15;
  const int wm   = wave >> 1, wn  = wave & 1;
  const int m0   = blockIdx.x * 128, n0 = blockIdx.y * 128;

  const int band = n0 >> 10;
  const float* bias = (band == 0) ? b0 : (band == 1) ? b1 : b2;

  const int srow = lane >> 3;          // 0..7
  const int sg   = lane & 7;           // 16B-dest granule 0..7
  const size_t rgs = (size_t)8 * K;    // 8-row group stride (elements)
  const float* aSrcF = Asrc + (size_t)(m0 + wave * 32 + srow) * K + sg * 8;
  const bf16*  wSrc  = W + (size_t)(n0 + wave * 32 + srow) * K + sg * 8;
  bf16* aDst = As + (wave * 32 + srow) * 64 + ((sg ^ srow) * 8);
  bf16* wDst = Bs + (wave * 32 + srow) * 64 + ((sg ^ srow) * 8);

  const int niter = K >> 6;

  // prefetch tile 0 (NAMED registers only -> no scratch)
  uint4 a0, a1, a2, a3;        // f32 path first halves
  uint4 a0h, a1h, a2h, a3h;    // f32 path second halves
  a0 = *(const uint4*)(aSrcF);            a0h = *(const uint4*)(aSrcF + 4);
  a1 = *(const uint4*)(aSrcF + rgs);      a1h = *(const uint4*)(aSrcF + rgs + 4);
  a2 = *(const uint4*)(aSrcF + 2 * rgs);  a2h = *(const uint4*)(aSrcF + 2 * rgs + 4);
  a3 = *(const uint4*)(aSrcF + 3 * rgs);  a3h = *(const uint4*)(aSrcF + 3 * rgs + 4);
  aSrcF += 64;
  uint4 w0 = *(const uint4*)(wSrc);
  uint4 w1 = *(const uint4*)(wSrc + rgs);
  uint4 w2 = *(const uint4*)(wSrc + 2 * rgs);
  uint4 w3 = *(const uint4*)(wSrc + 3 * rgs);
  wSrc += 64;

  f32x4 acc[4][4] = {};

  const int arow[4] = { (wm * 64 + 0 * 16 + l16) * 64, (wm * 64 + 1 * 16 + l16) * 64,
                        (wm * 64 + 2 * 16 + l16) * 64, (wm * 64 + 3 * 16 + l16) * 64 };
  const int brow[4] = { (wn * 64 + 0 * 16 + l16) * 64, (wn * 64 + 1 * 16 + l16) * 64,
                        (wn * 64 + 2 * 16 + l16) * 64, (wn * 64 + 3 * 16 + l16) * 64 };
  const int r7 = l16 & 7;

  for (int t = 0; t < niter; ++t) {
    if (t) barrier_lgkm();
    *(uint4*)(aDst)        = cvt8(a0, a0h);
    *(uint4*)(aDst + 512)  = cvt8(a1, a1h);
    *(uint4*)(aDst + 1024) = cvt8(a2, a2h);
    *(uint4*)(aDst + 1536) = cvt8(a3, a3h);
    *(uint4*)(wDst)        = w0;
    *(uint4*)(wDst + 512)  = w1;
    *(uint4*)(wDst + 1024) = w2;
    *(uint4*)(wDst + 1536) = w3;
    barrier_lgkm();                        // writes visible; vmem NOT drained
    if (t + 1 < niter) {                   // re-fill the same named regs
      a0 = *(const uint4*)(aSrcF);            a0h = *(const uint4*)(aSrcF + 4);
      a1 = *(const uint4*)(aSrcF + rgs);      a1h = *(const uint4*)(aSrcF + rgs + 4);
      a2 = *(const uint4*)(aSrcF + 2 * rgs);  a2h = *(const uint4*)(aSrcF + 2 * rgs + 4);
      a3 = *(const uint4*)(aSrcF + 3 * rgs);  a3h = *(const uint4*)(aSrcF + 3 * rgs + 4);
      aSrcF += 64;
      w0 = *(const uint4*)(wSrc);
      w1 = *(const uint4*)(wSrc + rgs);
      w2 = *(const uint4*)(wSrc + 2 * rgs);
      w3 = *(const uint4*)(wSrc + 3 * rgs);
      wSrc += 64;
    }
#pragma unroll
    for (int kk = 0; kk < 2; ++kk) {
      bf16x8 af[4], bw[4];
#pragma unroll
      for (int mt = 0; mt < 4; ++mt)
        af[mt] = *(const bf16x8*)(As + arow[mt] + (((kk * 4 + quad) ^ r7) * 8));
#pragma unroll
      for (int nt = 0; nt < 4; ++nt)
        bw[nt] = *(const bf16x8*)(Bs + brow[nt] + (((kk * 4 + quad) ^ r7) * 8));
#pragma unroll
      for (int mt = 0; mt < 4; ++mt)
#pragma unroll
        for (int nt = 0; nt < 4; ++nt)
          acc[mt][nt] = MFMA(af[mt], bw[nt], acc[mt][nt]);
    }
  }

  // epilogue: C/D layout col = lane&15, row = quad*4 + reg
#pragma unroll
  for (int nt = 0; nt < 4; ++nt) {
    const int col = n0 + wn * 64 + nt * 16 + l16;
    const int cl  = col & 1023;
    const float bv = bias[cl];
#pragma unroll
    for (int mt = 0; mt < 4; ++mt) {
      const int rbase = m0 + wm * 64 + mt * 16 + quad * 4;
      if (band == 2) {
        // transposed V: vt[(b*16+h)*64 + d][token], 4 consecutive tokens packed
        const int hh = cl >> 6, dd = cl & 63;
        const int bb = rbase >> 12, tl = rbase & 4095;
        u16* dst = o2 + ((size_t)((bb * 16 + hh) * 64 + dd)) * 4096 + tl;
        uint2 pk;
        pk.x = pk2bf(acc[mt][nt][0] + bv, acc[mt][nt][1] + bv);
        pk.y = pk2bf(acc[mt][nt][2] + bv, acc[mt][nt][3] + bv);
        *(uint2*)dst = pk;
      } else {
        u16* dst = (band == 0) ? o0 : o1;
        const float sc = (band == 0) ? SL2E : 1.0f;
#pragma unroll
        for (int r = 0; r < 4; ++r)
          dst[(size_t)(rbase + r) * 1024 + cl] =
              f32_to_bf16_rtne((acc[mt][nt][r] + bv) * sc);
      }
    }
  }
}

// ---------------------------------------------------------------------------
// Out-projection: 128x128 GEMM, gload_lds + __syncthreads (m97 structure),
// 512 blocks, 32 KiB LDS -> multiple blocks/CU.  Best measured out-proj.
// ---------------------------------------------------------------------------
__global__ __launch_bounds__(256)
void gemm_out(const bf16* __restrict__ A, const bf16* __restrict__ W,
              const float* __restrict__ bias, float* __restrict__ out,
              int M, int N, int K)
{
  __shared__ bf16 As[128 * 64];
  __shared__ bf16 Bs[128 * 64];

  const int tid  = threadIdx.x;
  const int wave = tid >> 6, lane = tid & 63;
  const int quad = lane >> 4, l16 = lane & 15;
  const int wm   = wave >> 1, wn  = wave & 1;
  const int m0   = blockIdx.x * 128, n0 = blockIdx.y * 128;

  const int srow = lane >> 3;
  const int sg   = lane & 7;
  const size_t rgs = (size_t)8 * K;
  const bf16* aSrc = A + (size_t)(m0 + wave * 32 + srow) * K + ((sg ^ srow) * 8);
  const bf16* wSrc = W + (size_t)(n0 + wave * 32 + srow) * K + ((sg ^ srow) * 8);
  bf16* aB = As + wave * 32 * 64;
  bf16* wB = Bs + wave * 32 * 64;

  const int niter = K >> 6;

  f32x4 acc[4][4] = {};

  const int arow[4] = { (wm * 64 + 0 * 16 + l16) * 64, (wm * 64 + 1 * 16 + l16) * 64,
                        (wm * 64 + 2 * 16 + l16) * 64, (wm * 64 + 3 * 16 + l16) * 64 };
  const int brow[4] = { (wn * 64 + 0 * 16 + l16) * 64, (wn * 64 + 1 * 16 + l16) * 64,
                        (wn * 64 + 2 * 16 + l16) * 64, (wn * 64 + 3 * 16 + l16) * 64 };
  const int r7 = l16 & 7;

  for (int t = 0; t < niter; ++t) {
    gload_lds16(aSrc,            aB);
    gload_lds16(aSrc + rgs,      aB + 512);
    gload_lds16(aSrc + 2 * rgs,  aB + 1024);
    gload_lds16(aSrc + 3 * rgs,  aB + 1536);
    gload_lds16(wSrc,            wB);
    gload_lds16(wSrc + rgs,      wB + 512);
    gload_lds16(wSrc + 2 * rgs,  wB + 1024);
    gload_lds16(wSrc + 3 * rgs,  wB + 1536);
    aSrc += 64; wSrc += 64;
    __syncthreads();

#pragma unroll
    for (int kk = 0; kk < 2; ++kk) {
      bf16x8 af[4], bw[4];
#pragma unroll
      for (int mt = 0; mt < 4; ++mt)
        af[mt] = *(const bf16x8*)(As + arow[mt] + (((kk * 4 + quad) ^ r7) * 8));
#pragma unroll
      for (int nt = 0; nt < 4; ++nt)
        bw[nt] = *(const bf16x8*)(Bs + brow[nt] + (((kk * 4 + quad) ^ r7) * 8));
#pragma unroll
      for (int mt = 0; mt < 4; ++mt)
#pragma unroll
        for (int nt = 0; nt < 4; ++nt)
          acc[mt][nt] = MFMA(af[mt], bw[nt], acc[mt][nt]);
    }
    if (t + 1 < niter) __syncthreads();
  }

#pragma unroll
  for (int nt = 0; nt < 4; ++nt) {
    const int col = n0 + wn * 64 + nt * 16 + l16;
    const float bv = bias[col & 1023];
#pragma unroll
    for (int mt = 0; mt < 4; ++mt) {
      const int rbase = m0 + wm * 64 + mt * 16 + quad * 4;
#pragma unroll
      for (int r = 0; r < 4; ++r)
        out[(size_t)(rbase + r) * N + col] = acc[mt][nt][r] + bv;
    }
  }
}

// ---------------------------------------------------------------------------
// Sliding-window attention, S^T formulation, fixed-max softmax,
// double-buffered K/V LDS, one lgkm barrier per tile (original, proven).
// ---------------------------------------------------------------------------
__global__ __launch_bounds__(256)
void attn_swin(const bf16* __restrict__ qb, const bf16* __restrict__ kb,
               const bf16* __restrict__ vtb, u16* __restrict__ ctx)
{
  __shared__ __align__(16) bf16 Ks[2][64 * 72];
  __shared__ __align__(16) bf16 Vts[2][64 * 72];

  int bid = blockIdx.x;
  const int g  = bid & 255, qt = bid >> 8;
  const int h  = g & 15, c = (g >> 4) & 7, b = g >> 7;

  const int tid  = threadIdx.x;
  const int w    = tid >> 6, lane = tid & 63;
  const int quad = lane >> 4, l16 = lane & 15;

  const int tq0  = c * 512 + qt * 128;
  const int hoff = h * 64;
  const int kstart = (c == 0) ? 0 : (c - 1) * 512;
  const int nkt    = (c == 0) ? 8 : 16;     // always even

  bf16x8 qf[2][2];
#pragma unroll
  for (int u = 0; u < 2; ++u) {
    const bf16* qr = qb + ((size_t)(b * 4096 + tq0 + w * 32 + u * 16 + l16)) * 1024 + hoff;
    qf[u][0] = *(const bf16x8*)(qr + quad * 8);
    qf[u][1] = *(const bf16x8*)(qr + 32 + quad * 8);
  }

  const int m    = tid >> 2;
  const int cseg = (tid & 3) * 16;
  const int sig  = (((m >> 4) & 1) << 5) | (((m >> 2) & 3) << 3)
                 | (((m >> 5) & 1) << 2) | (m & 3);
  const bf16* kgp = kb + ((size_t)(b * 4096 + kstart + sig)) * 1024 + hoff + cseg;
  const bf16* vgp = vtb + ((size_t)((b * 16 + h) * 64 + m)) * 4096 + kstart + cseg;
  const int soff = m * 72 + cseg;

  float l_i[2] = {0.f, 0.f};
  f32x4 o[2][4] = {};

  uint4 ka0 = *(const uint4*)(kgp), ka1 = *(const uint4*)(kgp + 8);
  uint4 va0 = *(const uint4*)(vgp), va1 = *(const uint4*)(vgp + 8);
  kgp += (size_t)64 * 1024; vgp += 64;
  *(uint4*)(Ks[0] + soff) = ka0; *(uint4*)(Ks[0] + soff + 8) = ka1;
  *(uint4*)(Vts[0] + soff) = va0; *(uint4*)(Vts[0] + soff + 8) = va1;
  ka0 = *(const uint4*)(kgp); ka1 = *(const uint4*)(kgp + 8);
  va0 = *(const uint4*)(vgp); va1 = *(const uint4*)(vgp + 8);
  kgp += (size_t)64 * 1024; vgp += 64;
  barrier_lgkm();

  typedef union { u32 d[4]; bf16x8 v; } fragu;

  auto compute = [&](const bf16* ksb, const bf16* vtsb) {
    f32x4 s[2][4] = {};
#pragma unroll
    for (int kt = 0; kt < 4; ++kt) {
      const bf16* kr = ksb + (kt * 16 + l16) * 72;
      bf16x8 kf0 = *(const bf16x8*)(kr + quad * 8);
      bf16x8 kf1 = *(const bf16x8*)(kr + 32 + quad * 8);
      s[0][kt] = MFMA(kf0, qf[0][0], s[0][kt]);
      s[0][kt] = MFMA(kf1, qf[0][1], s[0][kt]);
      s[1][kt] = MFMA(kf0, qf[1][0], s[1][kt]);
      s[1][kt] = MFMA(kf1, qf[1][1], s[1][kt]);
    }
    fragu pf[2][2];
#pragma unroll
    for (int u = 0; u < 2; ++u) {
      float rs = 0.f;
#pragma unroll
      for (int kt = 0; kt < 4; ++kt)
#pragma unroll
        for (int r = 0; r < 4; ++r) {
          const float p = __builtin_amdgcn_exp2f(s[u][kt][r]);
          s[u][kt][r] = p;
          rs += p;
        }
      rs += __shfl_xor(rs, 16);
      rs += __shfl_xor(rs, 32);
      l_i[u] += rs;
#pragma unroll
      for (int hh = 0; hh < 2; ++hh)
#pragma unroll
        for (int dw = 0; dw < 4; ++dw) {
          const int kt = 2 * (dw >> 1) + hh, r0 = 2 * (dw & 1);
          pf[u][hh].d[dw] = pk2bf_rtz(s[u][kt][r0], s[u][kt][r0 + 1]);
        }
    }
#pragma unroll
    for (int dt = 0; dt < 4; ++dt) {
      const bf16* vr = vtsb + (dt * 16 + l16) * 72;
      bf16x8 vf0 = *(const bf16x8*)(vr + quad * 8);
      bf16x8 vf1 = *(const bf16x8*)(vr + 32 + quad * 8);
      o[0][dt] = MFMA(vf0, pf[0][0].v, o[0][dt]);
      o[0][dt] = MFMA(vf1, pf[0][1].v, o[0][dt]);
      o[1][dt] = MFMA(vf0, pf[1][0].v, o[1][dt]);
      o[1][dt] = MFMA(vf1, pf[1][1].v, o[1][dt]);
    }
  };

  for (int t = 0; t < nkt; t += 2) {
    *(uint4*)(Ks[1] + soff) = ka0; *(uint4*)(Ks[1] + soff + 8) = ka1;
    *(uint4*)(Vts[1] + soff) = va0; *(uint4*)(Vts[1] + soff + 8) = va1;
    if (t + 2 < nkt) {
      ka0 = *(const uint4*)(kgp); ka1 = *(const uint4*)(kgp + 8);
      va0 = *(const uint4*)(vgp); va1 = *(const uint4*)(vgp + 8);
      kgp += (size_t)64 * 1024; vgp += 64;
    }
    compute(Ks[0], Vts[0]);
    barrier_lgkm();

    if (t + 2 < nkt) {
      *(uint4*)(Ks[0] + soff) = ka0; *(uint4*)(Ks[0] + soff + 8) = ka1;
      *(uint4*)(Vts[0] + soff) = va0; *(uint4*)(Vts[0] + soff + 8) = va1;
      if (t + 3 < nkt) {
        ka0 = *(const uint4*)(kgp); ka1 = *(const uint4*)(kgp + 8);
        va0 = *(const uint4*)(vgp); va1 = *(const uint4*)(vgp + 8);
        kgp += (size_t)64 * 1024; vgp += 64;
      }
    }
    compute(Ks[1], Vts[1]);
    barrier_lgkm();
  }

#pragma unroll
  for (int u = 0; u < 2; ++u) {
    const float inv = 1.0f / l_i[u];
    const int qrow = tq0 + w * 32 + u * 16 + l16;
    u16* crow = ctx + ((size_t)(b * 4096 + qrow)) * 1024 + hoff;
#pragma unroll
    for (int dt = 0; dt < 4; ++dt) {
      uint2 pk;
      pk.x = pk2bf(o[u][dt][0] * inv, o[u][dt][1] * inv);
      pk.y = pk2bf(o[u][dt][2] * inv, o[u][dt][3] * inv);
      *(uint2*)(crow + dt * 16 + quad * 4) = pk;
    }
  }
}

// ---------------------------------------------------------------------------
extern "C" void kernel_launch(void* const* d_in, const int* in_sizes, int n_in,
                              void* d_out, int out_size, void* d_ws, size_t ws_size,
                              hipStream_t stream) {
  const float* x  = (const float*)d_in[0];
  const float* Wq = (const float*)d_in[1];
  const float* bq = (const float*)d_in[2];
  const float* Wk = (const float*)d_in[3];
  const float* bk = (const float*)d_in[4];
  const float* Wv = (const float*)d_in[5];
  const float* bv = (const float*)d_in[6];
  const float* Wo = (const float*)d_in[7];
  const float* bo = (const float*)d_in[8];

  const size_t MD = (size_t)8192 * 1024;   // [B*L, D] elements
  const size_t DD = (size_t)1024 * 1024;   // [D, D] elements

  char* ws = (char*)d_ws;
  u16*  Wqkvb = (u16*)ws;                     ws += 3 * DD * 2;
  u16*  Wob   = (u16*)ws;                     ws += DD * 2;
  u16*  qbuf  = (u16*)ws;                     ws += MD * 2;
  u16*  kbuf  = (u16*)ws;                     ws += MD * 2;
  u16*  vtb   = (u16*)ws;                     ws += MD * 2;
  u16*  ctx   = (u16*)ws;                     // + MD*2  (~72 MB total)

  cast_w<<<dim3(2048), dim3(256), 0, stream>>>(Wq, Wk, Wv, Wo, Wqkvb, Wob);

  // fused QKV projection; A = x (f32) cast to bf16 inside the staging path
  gemm_bt<<<dim3(64, 24), dim3(256), 0, stream>>>(
      x, (const bf16*)Wqkvb, bq, bk, bv, qbuf, kbuf, vtb, 8192, 3072, 1024);

  attn_swin<<<dim3(1024), dim3(256), 0, stream>>>(
      (const bf16*)qbuf, (const bf16*)kbuf, (const bf16*)vtb, ctx);

  gemm_out<<<dim3(64, 8), dim3(256), 0, stream>>>(
      (const bf16*)ctx, (const bf16*)Wob, bo, (float*)d_out, 8192, 1024, 1024);
}